// Round 9
// baseline (1227.638 us; speedup 1.0000x reference)
//
#include <hip/hip_runtime.h>
#include <hip/hip_bf16.h>

#define Bdim 64
#define Gdim 1024
#define Ddim 256
#define Fdim 1024

typedef short s8v __attribute__((ext_vector_type(8)));
typedef short s4v __attribute__((ext_vector_type(4)));
typedef float f4v __attribute__((ext_vector_type(4)));

__device__ __forceinline__ float bf2f(short s){
  return __uint_as_float(((unsigned)(unsigned short)s) << 16);
}
__device__ __forceinline__ short f2bf(float f){
  unsigned u = __float_as_uint(f);
  u = u + 0x7fffu + ((u >> 16) & 1u);   // RNE
  return (short)(u >> 16);
}
__device__ __forceinline__ s8v ld8(const short* p){ return *(const s8v*)p; }

#define MFMA_BF16(a,b,c) __builtin_amdgcn_mfma_f32_16x16x32_bf16((a),(b),(c),0,0,0)

// async 16B global->LDS (linear dest; swizzle done on the SOURCE address)
#define GLDS16(gp, lp) __builtin_amdgcn_global_load_lds( \
    (const __attribute__((address_space(1))) void*)(gp), \
    (__attribute__((address_space(3))) void*)(lp), 16, 0, 0)

// ------------------------------------------------------------ dtype detection
__global__ __launch_bounds__(256) void detect_dtype(const unsigned* __restrict__ x,
                                                    int* __restrict__ flag){
  __shared__ int cnt[256];
  int c = 0;
  #pragma unroll
  for (int j=0;j<4;j++){
    unsigned u = x[threadIdx.x*4 + j];
    int e = (u >> 7) & 0xFF;
    c += (e >= 100 && e <= 140) ? 1 : 0;
  }
  cnt[threadIdx.x] = c;
  __syncthreads();
  if (threadIdx.x == 0){
    int s = 0;
    for (int i=0;i<256;i++) s += cnt[i];
    flag[0] = (s >= 512) ? 0 : 1;   // 0 = bf16 inputs, 1 = fp32 inputs
  }
}

// ------------------------------------------------------------ diagnostic
__global__ void diag_ws(void* o, float v, const int* __restrict__ flag){
  if (threadIdx.x == 0){
    if (flag[0]){ ((float*)o)[0] = v; ((float*)o)[16777216] = v; }
    else        { ((short*)o)[0] = f2bf(v); ((short*)o)[16777216] = f2bf(v); }
  }
}

// ------------------------------------------------------------ input -> fp32 h
__global__ __launch_bounds__(256) void cast_in(const void* __restrict__ x,
                                               float* __restrict__ h32,
                                               const int* __restrict__ flag){
  size_t i = ((size_t)blockIdx.x * 256 + threadIdx.x) * 8;
  if (flag[0]){
    const float* xf = (const float*)x;
    #pragma unroll
    for (int j=0;j<8;j++) h32[i+j] = xf[i+j];
  } else {
    s8v v = ld8((const short*)x + i);
    #pragma unroll
    for (int j=0;j<8;j++) h32[i+j] = bf2f(v[j]);
  }
}

// ------------------------------------------------------------ weight transpose -> bf16, stackable dst
__global__ __launch_bounds__(256) void transpose_w(const void* __restrict__ src,
                                                   short* __restrict__ dh, int R, int C,
                                                   const int* __restrict__ flag,
                                                   int dzs, int dbase){
  __shared__ short th[32][33];
  int fl = flag[0];
  size_t soff = (size_t)blockIdx.z * R * C;
  size_t doff = (size_t)dbase + (size_t)blockIdx.z * dzs;
  int c0 = blockIdx.x*32, r0 = blockIdx.y*32;
  int tx = threadIdx.x, ty = threadIdx.y;
  #pragma unroll
  for (int i=ty;i<32;i+=8){
    size_t idx = soff + (size_t)(r0+i)*C + (c0+tx);
    float w = fl ? ((const float*)src)[idx] : bf2f(((const short*)src)[idx]);
    th[i][tx] = f2bf(w);
  }
  __syncthreads();
  #pragma unroll
  for (int i=ty;i<32;i+=8)
    dh[doff + (size_t)(c0+i)*R + (r0+tx)] = th[tx][i];
}

// ------------------------------------------------------------ biases -> fp32
// [0..511]=bo(2x256)  [512..2559]=bf1(2x1024)  [2560..3071]=bf2(2x256)
__global__ __launch_bounds__(256) void bias_prep(const void* __restrict__ bo,
                                                 const void* __restrict__ bf1,
                                                 const void* __restrict__ bf2,
                                                 float* __restrict__ biasf,
                                                 const int* __restrict__ flag){
  int fl = flag[0];
  int i = blockIdx.x*256 + threadIdx.x;
  const void* src; int idx;
  if (i < 512){ src = bo; idx = i; }
  else if (i < 2560){ src = bf1; idx = i - 512; }
  else { src = bf2; idx = i - 2560; }
  biasf[i] = fl ? ((const float*)src)[idx] : bf2f(((const short*)src)[idx]);
}

// ------------------------------------------------------------ GEMM template (v2: m97-style pipeline)
// Double-buffered A/B LDS tiles [2][128][32] (linear dest for global_load_lds,
// XOR slot-swizzle slot^(row&3) applied on SOURCE addresses and on reads).
// B always bf16 -> GLDS16. A: AM=0 -> GLDS16; AM=1/2 -> reg-stage (loads
// issued before MFMA cluster, convert+ds_write after = T14 split).
// ONE __syncthreads per K-step (drains vmcnt for GLDS16 + lgkm for ds_write).
// AM: 0 = A bf16; 1 = A fp32 -> hi only; 2 = A fp32 -> hi+lo split (2 MFMA)
// EPI: 0 = bf16 store; 1 = relu(acc+bias) bf16 store;
//      4 = h32[idx] += acc + bias; 5 = fused QKV routing (Q,K row-major; V transposed)
template<int AM, int EPI>
__global__ __launch_bounds__(256) void gemm_t(
    const void* __restrict__ Ap, const short* __restrict__ Bh,
    const float* __restrict__ bias, float* __restrict__ hout,
    short* __restrict__ outb, int N, int K, int lda, int ldb, int Mrows)
{
  __shared__ short As[2][128*32];
  __shared__ short Bs[2][128*32];
  __shared__ short Asl[(AM==2)?2:1][(AM==2)?128*32:1];
  const int tid = threadIdx.x;
  const int lane = tid & 63, wave = tid >> 6;
  const int quad = lane >> 4, l16 = lane & 15;
  const int m0 = blockIdx.x * 128, n0 = blockIdx.y * 128;
  const int wr = wave >> 1, wc = wave & 1;
  const int roff = ((quad ^ (l16 & 3)) << 3);   // read-side swizzled 16B slot
  f4v acc[4][4];
  #pragma unroll
  for (int i=0;i<4;i++)
    #pragma unroll
    for (int j=0;j<4;j++) acc[i][j] = f4v{0.f,0.f,0.f,0.f};

  // per-thread staging geometry: 512 x 16B chunks per tile, 2 per thread
  int rr[2], ss[2], dst[2];
  #pragma unroll
  for (int i=0;i<2;i++){
    int idx = i*256 + tid;
    rr[i] = idx >> 2;
    ss[i] = (idx & 3) ^ (rr[i] & 3);   // source slot (inverse swizzle)
    dst[i] = idx * 8;                  // dest short index (linear)
  }

  auto stageB = [&](int buf, int k0){
    #pragma unroll
    for (int i=0;i<2;i++)
      GLDS16(Bh + (size_t)(n0 + rr[i])*ldb + k0 + ss[i]*8, &Bs[buf][dst[i]]);
  };
  auto stageA0 = [&](int buf, int k0){
    #pragma unroll
    for (int i=0;i<2;i++)
      GLDS16((const short*)Ap + (size_t)(m0 + rr[i])*lda + k0 + ss[i]*8, &As[buf][dst[i]]);
  };

  const int T = K >> 5;
  int cur = 0;
  // prologue: stage tile 0
  float4 pf0a, pf0b, pf1a, pf1b;
  stageB(0, 0);
  if (AM == 0){
    stageA0(0, 0);
  } else {
    #pragma unroll
    for (int i=0;i<2;i++){
      const float* ap = (const float*)Ap + (size_t)(m0 + rr[i])*lda + ss[i]*8;
      float4 a = *(const float4*)ap, b = *(const float4*)(ap + 4);
      float fv[8] = {a.x,a.y,a.z,a.w,b.x,b.y,b.z,b.w};
      s8v hi, lo;
      #pragma unroll
      for (int j=0;j<8;j++) hi[j] = f2bf(fv[j]);
      *(s8v*)(&As[0][dst[i]]) = hi;
      if (AM == 2){
        #pragma unroll
        for (int j=0;j<8;j++) lo[j] = f2bf(fv[j] - bf2f(hi[j]));
        *(s8v*)(&Asl[0][dst[i]]) = lo;
      }
    }
  }

  for (int t = 0; t < T; ++t){
    __syncthreads();                   // stage(cur) complete; prev reads done
    const int nk = (t + 1) << 5;
    if (t + 1 < T){                    // issue next-tile staging early
      stageB(cur ^ 1, nk);
      if (AM == 0){
        stageA0(cur ^ 1, nk);
      } else {
        const float* ap0 = (const float*)Ap + (size_t)(m0 + rr[0])*lda + nk + ss[0]*8;
        const float* ap1 = (const float*)Ap + (size_t)(m0 + rr[1])*lda + nk + ss[1]*8;
        pf0a = *(const float4*)ap0; pf0b = *(const float4*)(ap0 + 4);
        pf1a = *(const float4*)ap1; pf1b = *(const float4*)(ap1 + 4);
      }
    }
    // fragments from cur (swizzled reads)
    s8v ah[4], al[4], bh[4];
    #pragma unroll
    for (int q=0;q<4;q++){
      ah[q] = ld8(&As[cur][(wr*64 + q*16 + l16)*32 + roff]);
      bh[q] = ld8(&Bs[cur][(wc*64 + q*16 + l16)*32 + roff]);
      if (AM == 2) al[q] = ld8(&Asl[cur][(wr*64 + q*16 + l16)*32 + roff]);
    }
    __builtin_amdgcn_s_setprio(1);
    #pragma unroll
    for (int ti=0;ti<4;ti++)
      #pragma unroll
      for (int tj=0;tj<4;tj++){
        acc[ti][tj] = MFMA_BF16(ah[ti], bh[tj], acc[ti][tj]);
        if (AM == 2) acc[ti][tj] = MFMA_BF16(al[ti], bh[tj], acc[ti][tj]);
      }
    __builtin_amdgcn_s_setprio(0);
    if (AM != 0 && t + 1 < T){         // convert + write A(t+1) after compute
      float fv0[8] = {pf0a.x,pf0a.y,pf0a.z,pf0a.w,pf0b.x,pf0b.y,pf0b.z,pf0b.w};
      float fv1[8] = {pf1a.x,pf1a.y,pf1a.z,pf1a.w,pf1b.x,pf1b.y,pf1b.z,pf1b.w};
      s8v hi0, hi1, lo0, lo1;
      #pragma unroll
      for (int j=0;j<8;j++){ hi0[j] = f2bf(fv0[j]); hi1[j] = f2bf(fv1[j]); }
      *(s8v*)(&As[cur^1][dst[0]]) = hi0;
      *(s8v*)(&As[cur^1][dst[1]]) = hi1;
      if (AM == 2){
        #pragma unroll
        for (int j=0;j<8;j++){
          lo0[j] = f2bf(fv0[j] - bf2f(hi0[j]));
          lo1[j] = f2bf(fv1[j] - bf2f(hi1[j]));
        }
        *(s8v*)(&Asl[cur^1][dst[0]]) = lo0;
        *(s8v*)(&Asl[cur^1][dst[1]]) = lo1;
      }
    }
    cur ^= 1;
  }
  #pragma unroll
  for (int tj=0;tj<4;tj++){
    int col = n0 + wc*64 + tj*16 + l16;
    float bs = (EPI==1 || EPI==4) ? (bias ? bias[col] : 0.f) : 0.f;
    #pragma unroll
    for (int ti=0;ti<4;ti++){
      #pragma unroll
      for (int r=0;r<4;r++){
        int row = m0 + wr*64 + ti*16 + quad*4 + r;
        float v = acc[ti][tj][r];
        if (EPI == 0){
          outb[(size_t)row * N + col] = f2bf(v);
        } else if (EPI == 1){
          v += bs; v = v > 0.f ? v : 0.f;
          outb[(size_t)row * N + col] = f2bf(v);
        } else if (EPI == 4){
          size_t idx = (size_t)row * N + col;
          hout[idx] += v + bs;
        } else {  // EPI == 5: fused QKV
          int sec = col >> 8, c = col & 255;
          if (sec == 0)      outb[(size_t)row*256 + c] = f2bf(v);
          else if (sec == 1) (outb + (size_t)Mrows*256)[(size_t)row*256 + c] = f2bf(v);
          else {
            int bb = row >> 10, g = row & 1023;
            (outb + (size_t)2*Mrows*256)[(size_t)bb*262144 + (size_t)c*1024 + g] = f2bf(v);
          }
        }
      }
    }
  }
}

// ------------------------------------------------------------ flash attention v8
// Same per-wave structure as v4 (best measured), but 4-wave/64-row blocks with
// KVBLK=32 -> LDS 69.25KB -> TWO INDEPENDENT blocks per CU (grid 16*CB = 512).
// Same 8 waves/CU, but the two blocks are barrier-decoupled: while block A
// drains its __syncthreads or runs its serial softmax chain, block B's waves
// feed the MFMA/DS pipes. K,V double-buffered via global_load_lds
// (lane-linear dest, XOR-pre-swizzled source, same XOR on ds_read). One
// __syncthreads per kt (32 kts). Deferred sum-reduce; setprio on MFMA.
__global__ __launch_bounds__(256, 2) void flash_attn(
    const short* __restrict__ Q, const short* __restrict__ Kmat,
    const short* __restrict__ Vt, const int* __restrict__ mask,
    short* __restrict__ H)
{
  __shared__ short Ks[2][32*256];   // 32 KiB: K tile [32 keys][256 d], src-swizzled
  __shared__ short Vs[2][256*32];   // 32 KiB: V^T tile [256 d][32 keys], src-swizzled
  __shared__ short Ps[4][16*40];    // 5 KiB: per-wave P [16 q][32 keys], stride 40
  const int tid = threadIdx.x;
  const int lane = tid & 63, wave = tid >> 6;   // wave 0..3
  const int quad = lane >> 4, l16 = lane & 15;
  // batch -> XCD pinning: all 16 q-tile blocks of batch b share XCD b&7.
  // bid = (b&7) + 8*qt + 128*(b>>3)  (bijective for CB in {16,32,64})
  const int bid = blockIdx.x;
  const int b  = (bid & 7) + ((bid >> 7) << 3);
  const int qt = (bid >> 3) & 15;
  const short* Qb  = Q    + (size_t)b*Gdim*Ddim;
  const short* Kb  = Kmat + (size_t)b*Gdim*Ddim;
  const short* Vtb = Vt   + (size_t)b*Ddim*Gdim;
  const int qbase = qt*64 + wave*16;

  auto stage = [&](int buf, int k0){
    #pragma unroll
    for (int i=0;i<4;i++){            // K tile: 16 KiB, 16B/thread x 4
      int idx = i*256 + tid;
      int r = idx >> 5, g = idx & 31;
      GLDS16(Kb + (size_t)(k0 + r)*Ddim + ((g ^ (r & 7)) << 3), &Ks[buf][idx*8]);
    }
    #pragma unroll
    for (int i=0;i<4;i++){            // V^T tile: 16 KiB (4 slots/row)
      int idx = i*256 + tid;
      int d = idx >> 2, g = idx & 3;
      GLDS16(Vtb + (size_t)d*Gdim + k0 + ((g ^ (d & 3)) << 3), &Vs[buf][idx*8]);
    }
  };

  s8v qf[8];
  #pragma unroll
  for (int s=0;s<8;s++)
    qf[s] = ld8(Qb + (size_t)(qbase + l16)*Ddim + s*32 + quad*8);
  float mrow[4], lsum[4];
  #pragma unroll
  for (int r=0;r<4;r++){ mrow[r] = -1e9f; lsum[r] = 0.f; }
  f4v O[16];
  #pragma unroll
  for (int t=0;t<16;t++) O[t] = f4v{0.f,0.f,0.f,0.f};
  short* Pw = Ps[wave];

  stage(0, 0);
  __syncthreads();
  int cur = 0;
  for (int kt=0; kt<32; kt++){
    const int k0 = kt*32;
    if (kt < 31) stage(cur^1, k0 + 32);   // prefetch next tile, other buffer
    int mk[2];
    #pragma unroll
    for (int tj=0;tj<2;tj++) mk[tj] = mask[b*Gdim + k0 + tj*16 + l16];
    // ---- QK^T from LDS (swizzled reads)
    f4v sc[2];
    sc[0] = f4v{0.f,0.f,0.f,0.f};
    sc[1] = f4v{0.f,0.f,0.f,0.f};
    const short* Kc = &Ks[cur][0];
    __builtin_amdgcn_s_setprio(1);
    #pragma unroll
    for (int st=0; st<8; st++){
      #pragma unroll
      for (int tj=0;tj<2;tj++){
        int row = tj*16 + l16;
        s8v kb = ld8(Kc + row*256 + (((st*4 + quad) ^ (row & 7)) << 3));
        sc[tj] = MFMA_BF16(qf[st], kb, sc[tj]);
      }
    }
    __builtin_amdgcn_s_setprio(0);
    // ---- online softmax; masked -> -30, stays in denominator, zeroed in
    //      numerator. Sum-reduce deferred: lsum is a PER-LANE partial.
    float al[4]; bool need = false;
    #pragma unroll
    for (int r=0;r<4;r++){
      float mx = -1e9f;
      #pragma unroll
      for (int tj=0;tj<2;tj++){
        float v = sc[tj][r] * 0.0625f;
        if (mk[tj]) v = -30.f;
        sc[tj][r] = v;
        mx = fmaxf(mx, v);
      }
      #pragma unroll
      for (int mm=1; mm<16; mm<<=1) mx = fmaxf(mx, __shfl_xor(mx, mm));
      float mn = fmaxf(mrow[r], mx);
      al[r] = __expf(mrow[r] - mn);
      need |= (al[r] < 1.f);
      mrow[r] = mn;
      float ps = 0.f;
      #pragma unroll
      for (int tj=0;tj<2;tj++){
        float e = __expf(sc[tj][r] - mn);
        ps += e;                         // masked entries stay in denominator
        sc[tj][r] = mk[tj] ? 0.f : e;    // zeroed in numerator
      }
      lsum[r] = lsum[r]*al[r] + ps;      // per-lane partial; no reduce here
    }
    if (__any(need)){
      #pragma unroll
      for (int t=0;t<16;t++)
        #pragma unroll
        for (int r=0;r<4;r++) O[t][r] *= al[r];
    }
    // ---- P transpose through wave-private LDS (intra-wave ordering only)
    #pragma unroll
    for (int tj=0;tj<2;tj++)
      #pragma unroll
      for (int r=0;r<4;r++)
        Pw[(quad*4 + r)*40 + tj*16 + l16] = f2bf(sc[tj][r]);
    asm volatile("s_waitcnt lgkmcnt(0)" ::: "memory");
    __builtin_amdgcn_sched_barrier(0);
    // ---- PV from LDS (swizzled reads); K=32 -> one A-frag
    const short* Vc = &Vs[cur][0];
    __builtin_amdgcn_s_setprio(1);
    s8v pa = ld8(&Pw[l16*40 + quad*8]);
    #pragma unroll
    for (int tt=0; tt<16; tt++){
      int d = tt*16 + l16;
      s8v vb = ld8(Vc + d*32 + ((quad ^ (d & 3)) << 3));
      O[tt] = MFMA_BF16(pa, vb, O[tt]);
    }
    __builtin_amdgcn_s_setprio(0);
    __syncthreads();   // drains vmcnt (prefetch done) + lgkm; flip safe
    cur ^= 1;
  }
  // ---- deferred cross-lane sum reduce (once, not per kt)
  float dn[4];
  #pragma unroll
  for (int r=0;r<4;r++){
    float s = lsum[r];
    #pragma unroll
    for (int mm=1; mm<16; mm<<=1) s += __shfl_xor(s, mm);
    dn[r] = fmaxf(s, 1e-30f);
  }
  #pragma unroll
  for (int t=0;t<16;t++){
    #pragma unroll
    for (int r=0;r<4;r++){
      int row = qbase + quad*4 + r;
      int col = t*16 + l16;
      H[((size_t)b*Gdim + row)*Ddim + col] = f2bf(O[t][r] / dn[r]);
    }
  }
}

// ------------------------------------------------------------ mean + output
__global__ __launch_bounds__(256) void mean_partial(const float* __restrict__ h32,
                                                    float* __restrict__ part){
  int b = blockIdx.x, c = blockIdx.y, d = threadIdx.x;
  float s = 0.f;
  for (int g = c*64; g < c*64 + 64; g++)
    s += h32[((size_t)b*Gdim + g)*Ddim + d];
  part[(b*16 + c)*Ddim + d] = s;
}
__global__ __launch_bounds__(256) void mean_final_dyn(const float* __restrict__ part,
                                                      void* __restrict__ out,
                                                      const int* __restrict__ flag){
  int i = blockIdx.x*256 + threadIdx.x;
  int b = i >> 8, d = i & 255;
  float s = 0.f;
  #pragma unroll
  for (int c=0;c<16;c++) s += part[(b*16 + c)*Ddim + d];
  s *= (1.f/1024.f);
  if (flag[0]) ((float*)out)[16777216 + i] = s;
  else         ((short*)out)[16777216 + i] = f2bf(s);
}
__global__ __launch_bounds__(256) void store_h(const float* __restrict__ h32,
                                               void* __restrict__ out,
                                               const int* __restrict__ flag){
  size_t i = (size_t)blockIdx.x*256 + threadIdx.x;
  if (flag[0]) ((float*)out)[i] = h32[i];
  else         ((short*)out)[i] = f2bf(h32[i]);
}

// ------------------------------------------------------------ launch
extern "C" void kernel_launch(void* const* d_in, const int* in_sizes, int n_in,
                              void* d_out, int out_size, void* d_ws, size_t ws_size,
                              hipStream_t stream)
{
  const void* xs  = d_in[0];
  const int*  mask= (const int*)d_in[1];
  const void* Wq  = d_in[2];
  const void* Wk  = d_in[3];
  const void* Wv  = d_in[4];
  const void* Wo  = d_in[5];
  const void* bo  = d_in[6];
  const void* Wf1 = d_in[7];
  const void* bf1 = d_in[8];
  const void* Wf2 = d_in[9];
  const void* bf2 = d_in[10];

  // weights: Wqkv(768K) + Wo(256K) + Wf1(1M) + Wf2(1M) + biasf(12K)
  const size_t W_ALL = 786432 + 262144 + 1048576 + 1048576 + 12288;  // 3,158,016
  const size_t BASE  = 256 + 67108864;                               // flag + h32
  int CB;
  if      (ws_size >= BASE + 134217728ull + W_ALL) CB = 64;   // 204.5 MB
  else if (ws_size >= BASE +  67108864ull + W_ALL) CB = 32;   // 137.4 MB (proven reachable)
  else if (ws_size >= BASE +  33554432ull + W_ALL) CB = 16;
  else CB = 0;

  char* p = (char*)d_ws;
  int* flag = (int*)p; p += 256;
  detect_dtype<<<1, 256, 0, stream>>>((const unsigned*)xs, flag);
  if (CB == 0){
    diag_ws<<<1, 64, 0, stream>>>(d_out, 2000.f + (float)(ws_size >> 20), flag);
    return;
  }
  const int M = CB * 1024, nch = 64 / CB;
  float* h32 = (float*)p; p += 67108864;
  char* arena = p;        p += (size_t)CB * 2097152;
  short* WqkvT = (short*)p; p += 786432;
  short* WoT   = (short*)p; p += 262144;
  short* Wf1T  = (short*)p; p += 1048576;
  short* Wf2T  = (short*)p; p += 1048576;
  float* biasf = (float*)p; p += 12288;
  float* part  = (float*)arena;          // arena dead by mean time

  short* Qc  = (short*)arena;
  short* Kc  = Qc + (size_t)M*256;
  short* Vtc = Qc + (size_t)2*M*256;
  short* Hc  = Qc + (size_t)3*M*256;
  short* Tc  = Qc;                       // FFN intermediate spans whole arena

  cast_in<<<8192, 256, 0, stream>>>(xs, h32, flag);
  dim3 tb(32,8);
  transpose_w<<<dim3(8,8,2),  tb, 0, stream>>>(Wq,  WqkvT, 256, 256,  flag, 196608, 0);
  transpose_w<<<dim3(8,8,2),  tb, 0, stream>>>(Wk,  WqkvT, 256, 256,  flag, 196608, 65536);
  transpose_w<<<dim3(8,8,2),  tb, 0, stream>>>(Wv,  WqkvT, 256, 256,  flag, 196608, 131072);
  transpose_w<<<dim3(8,8,2),  tb, 0, stream>>>(Wo,  WoT,   256, 256,  flag, 65536, 0);
  transpose_w<<<dim3(32,8,2), tb, 0, stream>>>(Wf1, Wf1T,  256, 1024, flag, 262144, 0);
  transpose_w<<<dim3(8,32,2), tb, 0, stream>>>(Wf2, Wf2T,  1024, 256, flag, 262144, 0);
  bias_prep<<<12, 256, 0, stream>>>(bo, bf1, bf2, biasf, flag);

  for (int c=0; c<nch; c++){
    float* hc = h32 + (size_t)c*M*256;
    const int* mc = mask + (size_t)c*M;
    for (int l=0; l<2; l++){
      // fused QKV: A = h fp32 (hi), B = stacked [768][256]
      gemm_t<1,5><<<dim3(M/128,6), 256, 0, stream>>>(hc, WqkvT + l*196608, nullptr,
                                                     nullptr, Qc, 768, 256, 256, 256, M);
      flash_attn<<<dim3(16*CB), 256, 0, stream>>>(Qc, Kc, Vtc, mc, Hc);
      // O-proj: h32 += Hc*Wo + bo
      gemm_t<0,4><<<dim3(M/128,2), 256, 0, stream>>>(Hc, WoT + l*65536, biasf + l*256,
                                                     hc, nullptr, 256, 256, 256, 256, M);
      // FFN1: T = relu(h*Wf1 + b), A split
      gemm_t<2,1><<<dim3(M/128,8), 256, 0, stream>>>(hc, Wf1T + l*262144, biasf + 512 + l*1024,
                                                     nullptr, Tc, 1024, 256, 256, 256, M);
      // FFN2: h32 += T*Wf2 + b
      gemm_t<0,4><<<dim3(M/128,2), 256, 0, stream>>>(Tc, Wf2T + l*262144, biasf + 2560 + l*256,
                                                     hc, nullptr, 256, 1024, 1024, 1024, M);
    }
  }
  mean_partial<<<dim3(64,16), 256, 0, stream>>>(h32, part);
  store_h<<<65536, 256, 0, stream>>>(h32, d_out, flag);
  mean_final_dyn<<<64, 256, 0, stream>>>(part, d_out, flag);
}

// Round 10
// 1147.636 us; speedup vs baseline: 1.0697x; 1.0697x over previous
//
#include <hip/hip_runtime.h>
#include <hip/hip_bf16.h>

#define Bdim 64
#define Gdim 1024
#define Ddim 256
#define Fdim 1024

typedef short s8v __attribute__((ext_vector_type(8)));
typedef short s4v __attribute__((ext_vector_type(4)));
typedef float f4v __attribute__((ext_vector_type(4)));

__device__ __forceinline__ float bf2f(short s){
  return __uint_as_float(((unsigned)(unsigned short)s) << 16);
}
__device__ __forceinline__ short f2bf(float f){
  unsigned u = __float_as_uint(f);
  u = u + 0x7fffu + ((u >> 16) & 1u);   // RNE
  return (short)(u >> 16);
}
__device__ __forceinline__ s8v ld8(const short* p){ return *(const s8v*)p; }

#define MFMA_BF16(a,b,c) __builtin_amdgcn_mfma_f32_16x16x32_bf16((a),(b),(c),0,0,0)

// async 16B global->LDS (linear dest; swizzle done on the SOURCE address)
#define GLDS16(gp, lp) __builtin_amdgcn_global_load_lds( \
    (const __attribute__((address_space(1))) void*)(gp), \
    (__attribute__((address_space(3))) void*)(lp), 16, 0, 0)

// ------------------------------------------------------------ dtype detection
__global__ __launch_bounds__(256) void detect_dtype(const unsigned* __restrict__ x,
                                                    int* __restrict__ flag){
  __shared__ int cnt[256];
  int c = 0;
  #pragma unroll
  for (int j=0;j<4;j++){
    unsigned u = x[threadIdx.x*4 + j];
    int e = (u >> 7) & 0xFF;
    c += (e >= 100 && e <= 140) ? 1 : 0;
  }
  cnt[threadIdx.x] = c;
  __syncthreads();
  if (threadIdx.x == 0){
    int s = 0;
    for (int i=0;i<256;i++) s += cnt[i];
    flag[0] = (s >= 512) ? 0 : 1;   // 0 = bf16 inputs, 1 = fp32 inputs
  }
}

// ------------------------------------------------------------ diagnostic
__global__ void diag_ws(void* o, float v, const int* __restrict__ flag){
  if (threadIdx.x == 0){
    if (flag[0]){ ((float*)o)[0] = v; ((float*)o)[16777216] = v; }
    else        { ((short*)o)[0] = f2bf(v); ((short*)o)[16777216] = f2bf(v); }
  }
}

// ------------------------------------------------------------ input -> fp32 h
__global__ __launch_bounds__(256) void cast_in(const void* __restrict__ x,
                                               float* __restrict__ h32,
                                               const int* __restrict__ flag){
  size_t i = ((size_t)blockIdx.x * 256 + threadIdx.x) * 8;
  if (flag[0]){
    const float* xf = (const float*)x;
    #pragma unroll
    for (int j=0;j<8;j++) h32[i+j] = xf[i+j];
  } else {
    s8v v = ld8((const short*)x + i);
    #pragma unroll
    for (int j=0;j<8;j++) h32[i+j] = bf2f(v[j]);
  }
}

// ------------------------------------------------------------ weight transpose -> bf16, stackable dst
__global__ __launch_bounds__(256) void transpose_w(const void* __restrict__ src,
                                                   short* __restrict__ dh, int R, int C,
                                                   const int* __restrict__ flag,
                                                   int dzs, int dbase){
  __shared__ short th[32][33];
  int fl = flag[0];
  size_t soff = (size_t)blockIdx.z * R * C;
  size_t doff = (size_t)dbase + (size_t)blockIdx.z * dzs;
  int c0 = blockIdx.x*32, r0 = blockIdx.y*32;
  int tx = threadIdx.x, ty = threadIdx.y;
  #pragma unroll
  for (int i=ty;i<32;i+=8){
    size_t idx = soff + (size_t)(r0+i)*C + (c0+tx);
    float w = fl ? ((const float*)src)[idx] : bf2f(((const short*)src)[idx]);
    th[i][tx] = f2bf(w);
  }
  __syncthreads();
  #pragma unroll
  for (int i=ty;i<32;i+=8)
    dh[doff + (size_t)(c0+i)*R + (r0+tx)] = th[tx][i];
}

// ------------------------------------------------------------ V row-major -> V^T (bf16), per batch
// src: [CB][1024 g][256 d] row-major; dst: [CB][256 d][1024 g]
__global__ __launch_bounds__(256) void transpose_v(const short* __restrict__ src,
                                                   short* __restrict__ dst){
  __shared__ short th[32][33];
  const short* s = src + (size_t)blockIdx.z * 262144;
  short* dd      = dst + (size_t)blockIdx.z * 262144;
  int d0 = blockIdx.x*32, g0 = blockIdx.y*32;
  int tx = threadIdx.x, ty = threadIdx.y;
  #pragma unroll
  for (int i=ty;i<32;i+=8)
    th[i][tx] = s[(size_t)(g0+i)*256 + d0 + tx];
  __syncthreads();
  #pragma unroll
  for (int i=ty;i<32;i+=8)
    dd[(size_t)(d0+i)*1024 + g0 + tx] = th[tx][i];
}

// ------------------------------------------------------------ biases -> fp32
// [0..511]=bo(2x256)  [512..2559]=bf1(2x1024)  [2560..3071]=bf2(2x256)
__global__ __launch_bounds__(256) void bias_prep(const void* __restrict__ bo,
                                                 const void* __restrict__ bf1,
                                                 const void* __restrict__ bf2,
                                                 float* __restrict__ biasf,
                                                 const int* __restrict__ flag){
  int fl = flag[0];
  int i = blockIdx.x*256 + threadIdx.x;
  const void* src; int idx;
  if (i < 512){ src = bo; idx = i; }
  else if (i < 2560){ src = bf1; idx = i - 512; }
  else { src = bf2; idx = i - 2560; }
  biasf[i] = fl ? ((const float*)src)[idx] : bf2f(((const short*)src)[idx]);
}

// ------------------------------------------------------------ GEMM template (v2: m97-style pipeline)
// Double-buffered A/B LDS tiles [2][128][32] (linear dest for global_load_lds,
// XOR slot-swizzle slot^(row&3) applied on SOURCE addresses and on reads).
// B always bf16 -> GLDS16. A: AM=0 -> GLDS16; AM=1/2 -> reg-stage (loads
// issued before MFMA cluster, convert+ds_write after = T14 split).
// ONE __syncthreads per K-step (drains vmcnt for GLDS16 + lgkm for ds_write).
// AM: 0 = A bf16; 1 = A fp32 -> hi only; 2 = A fp32 -> hi+lo split (2 MFMA)
// EPI: 0 = bf16 store; 1 = relu(acc+bias) bf16 store;
//      4 = h32[idx] += acc + bias; 5 = fused QKV routing (Q,K row-major; V row-major to Hc slot)
template<int AM, int EPI>
__global__ __launch_bounds__(256) void gemm_t(
    const void* __restrict__ Ap, const short* __restrict__ Bh,
    const float* __restrict__ bias, float* __restrict__ hout,
    short* __restrict__ outb, int N, int K, int lda, int ldb, int Mrows)
{
  __shared__ short As[2][128*32];
  __shared__ short Bs[2][128*32];
  __shared__ short Asl[(AM==2)?2:1][(AM==2)?128*32:1];
  const int tid = threadIdx.x;
  const int lane = tid & 63, wave = tid >> 6;
  const int quad = lane >> 4, l16 = lane & 15;
  const int m0 = blockIdx.x * 128, n0 = blockIdx.y * 128;
  const int wr = wave >> 1, wc = wave & 1;
  const int roff = ((quad ^ (l16 & 3)) << 3);   // read-side swizzled 16B slot
  f4v acc[4][4];
  #pragma unroll
  for (int i=0;i<4;i++)
    #pragma unroll
    for (int j=0;j<4;j++) acc[i][j] = f4v{0.f,0.f,0.f,0.f};

  // per-thread staging geometry: 512 x 16B chunks per tile, 2 per thread
  int rr[2], ss[2], dst[2];
  #pragma unroll
  for (int i=0;i<2;i++){
    int idx = i*256 + tid;
    rr[i] = idx >> 2;
    ss[i] = (idx & 3) ^ (rr[i] & 3);   // source slot (inverse swizzle)
    dst[i] = idx * 8;                  // dest short index (linear)
  }

  auto stageB = [&](int buf, int k0){
    #pragma unroll
    for (int i=0;i<2;i++)
      GLDS16(Bh + (size_t)(n0 + rr[i])*ldb + k0 + ss[i]*8, &Bs[buf][dst[i]]);
  };
  auto stageA0 = [&](int buf, int k0){
    #pragma unroll
    for (int i=0;i<2;i++)
      GLDS16((const short*)Ap + (size_t)(m0 + rr[i])*lda + k0 + ss[i]*8, &As[buf][dst[i]]);
  };

  const int T = K >> 5;
  int cur = 0;
  // prologue: stage tile 0
  float4 pf0a, pf0b, pf1a, pf1b;
  stageB(0, 0);
  if (AM == 0){
    stageA0(0, 0);
  } else {
    #pragma unroll
    for (int i=0;i<2;i++){
      const float* ap = (const float*)Ap + (size_t)(m0 + rr[i])*lda + ss[i]*8;
      float4 a = *(const float4*)ap, b = *(const float4*)(ap + 4);
      float fv[8] = {a.x,a.y,a.z,a.w,b.x,b.y,b.z,b.w};
      s8v hi, lo;
      #pragma unroll
      for (int j=0;j<8;j++) hi[j] = f2bf(fv[j]);
      *(s8v*)(&As[0][dst[i]]) = hi;
      if (AM == 2){
        #pragma unroll
        for (int j=0;j<8;j++) lo[j] = f2bf(fv[j] - bf2f(hi[j]));
        *(s8v*)(&Asl[0][dst[i]]) = lo;
      }
    }
  }

  for (int t = 0; t < T; ++t){
    __syncthreads();                   // stage(cur) complete; prev reads done
    const int nk = (t + 1) << 5;
    if (t + 1 < T){                    // issue next-tile staging early
      stageB(cur ^ 1, nk);
      if (AM == 0){
        stageA0(cur ^ 1, nk);
      } else {
        const float* ap0 = (const float*)Ap + (size_t)(m0 + rr[0])*lda + nk + ss[0]*8;
        const float* ap1 = (const float*)Ap + (size_t)(m0 + rr[1])*lda + nk + ss[1]*8;
        pf0a = *(const float4*)ap0; pf0b = *(const float4*)(ap0 + 4);
        pf1a = *(const float4*)ap1; pf1b = *(const float4*)(ap1 + 4);
      }
    }
    // fragments from cur (swizzled reads)
    s8v ah[4], al[4], bh[4];
    #pragma unroll
    for (int q=0;q<4;q++){
      ah[q] = ld8(&As[cur][(wr*64 + q*16 + l16)*32 + roff]);
      bh[q] = ld8(&Bs[cur][(wc*64 + q*16 + l16)*32 + roff]);
      if (AM == 2) al[q] = ld8(&Asl[cur][(wr*64 + q*16 + l16)*32 + roff]);
    }
    __builtin_amdgcn_s_setprio(1);
    #pragma unroll
    for (int ti=0;ti<4;ti++)
      #pragma unroll
      for (int tj=0;tj<4;tj++){
        acc[ti][tj] = MFMA_BF16(ah[ti], bh[tj], acc[ti][tj]);
        if (AM == 2) acc[ti][tj] = MFMA_BF16(al[ti], bh[tj], acc[ti][tj]);
      }
    __builtin_amdgcn_s_setprio(0);
    if (AM != 0 && t + 1 < T){         // convert + write A(t+1) after compute
      float fv0[8] = {pf0a.x,pf0a.y,pf0a.z,pf0a.w,pf0b.x,pf0b.y,pf0b.z,pf0b.w};
      float fv1[8] = {pf1a.x,pf1a.y,pf1a.z,pf1a.w,pf1b.x,pf1b.y,pf1b.z,pf1b.w};
      s8v hi0, hi1, lo0, lo1;
      #pragma unroll
      for (int j=0;j<8;j++){ hi0[j] = f2bf(fv0[j]); hi1[j] = f2bf(fv1[j]); }
      *(s8v*)(&As[cur^1][dst[0]]) = hi0;
      *(s8v*)(&As[cur^1][dst[1]]) = hi1;
      if (AM == 2){
        #pragma unroll
        for (int j=0;j<8;j++){
          lo0[j] = f2bf(fv0[j] - bf2f(hi0[j]));
          lo1[j] = f2bf(fv1[j] - bf2f(hi1[j]));
        }
        *(s8v*)(&Asl[cur^1][dst[0]]) = lo0;
        *(s8v*)(&Asl[cur^1][dst[1]]) = lo1;
      }
    }
    cur ^= 1;
  }
  #pragma unroll
  for (int tj=0;tj<4;tj++){
    int col = n0 + wc*64 + tj*16 + l16;
    float bs = (EPI==1 || EPI==4) ? (bias ? bias[col] : 0.f) : 0.f;
    #pragma unroll
    for (int ti=0;ti<4;ti++){
      #pragma unroll
      for (int r=0;r<4;r++){
        int row = m0 + wr*64 + ti*16 + quad*4 + r;
        float v = acc[ti][tj][r];
        if (EPI == 0){
          outb[(size_t)row * N + col] = f2bf(v);
        } else if (EPI == 1){
          v += bs; v = v > 0.f ? v : 0.f;
          outb[(size_t)row * N + col] = f2bf(v);
        } else if (EPI == 4){
          size_t idx = (size_t)row * N + col;
          hout[idx] += v + bs;
        } else {  // EPI == 5: fused QKV; V goes ROW-MAJOR into the Hc slot
          int sec = col >> 8, c = col & 255;
          if (sec == 0)      outb[(size_t)row*256 + c] = f2bf(v);
          else if (sec == 1) (outb + (size_t)Mrows*256)[(size_t)row*256 + c] = f2bf(v);
          else               (outb + (size_t)3*Mrows*256)[(size_t)row*256 + c] = f2bf(v);
        }
      }
    }
  }
}

// ------------------------------------------------------------ flash attention v4 (best measured 142.7us)
// 8 waves x 16 q-rows = 128 rows/block; 8 blocks/batch; grid 8*CB; 512 thr ->
// 8 waves/CU = 2 waves/SIMD. K,V double-buffered in LDS via async
// global_load_lds (linear dest, XOR-pre-swizzled SOURCE, same XOR on ds_read).
// One __syncthreads per kt. Sum-reduce DEFERRED: per-lane partial lsum with
// the same rescale recurrence; single cross-lane reduce in the epilogue.
// setprio(1) wraps MFMA clusters.
__global__ __launch_bounds__(512, 2) void flash_attn(
    const short* __restrict__ Q, const short* __restrict__ Kmat,
    const short* __restrict__ Vt, const int* __restrict__ mask,
    short* __restrict__ H)
{
  __shared__ short Ks[2][64*256];   // 64 KiB: K tile [64 keys][256 d], src-swizzled
  __shared__ short Vs[2][256*64];   // 64 KiB: V^T tile [256 d][64 keys], src-swizzled
  __shared__ short Ps[8][16*72];    // 18 KiB: per-wave P [16 qrows][64 keys]
  const int tid = threadIdx.x;
  const int lane = tid & 63, wave = tid >> 6;   // wave 0..7
  const int quad = lane >> 4, l16 = lane & 15;
  // batch -> XCD pinning: all 8 q-tile blocks of batch b share XCD b&7.
  const int bid = blockIdx.x;
  const int b  = (bid & 7) + ((bid >> 6) << 3);
  const int qt = (bid >> 3) & 7;
  const short* Qb  = Q    + (size_t)b*Gdim*Ddim;
  const short* Kb  = Kmat + (size_t)b*Gdim*Ddim;
  const short* Vtb = Vt   + (size_t)b*Ddim*Gdim;
  const int qbase = qt*128 + wave*16;

  auto stage = [&](int buf, int k0){
    #pragma unroll
    for (int i=0;i<4;i++){            // K tile: 32 KiB, 16B/thread x 4
      int idx = i*512 + tid;
      int r = idx >> 5, g = idx & 31;
      GLDS16(Kb + (size_t)(k0 + r)*Ddim + ((g ^ (r & 7)) << 3), &Ks[buf][idx*8]);
    }
    #pragma unroll
    for (int i=0;i<4;i++){            // V^T tile: 32 KiB
      int idx = i*512 + tid;
      int d = idx >> 3, g = idx & 7;
      GLDS16(Vtb + (size_t)d*Gdim + k0 + ((g ^ (d & 7)) << 3), &Vs[buf][idx*8]);
    }
  };

  s8v qf[8];
  #pragma unroll
  for (int s=0;s<8;s++)
    qf[s] = ld8(Qb + (size_t)(qbase + l16)*Ddim + s*32 + quad*8);
  float mrow[4], lsum[4];
  #pragma unroll
  for (int r=0;r<4;r++){ mrow[r] = -1e9f; lsum[r] = 0.f; }
  f4v O[16];
  #pragma unroll
  for (int t=0;t<16;t++) O[t] = f4v{0.f,0.f,0.f,0.f};
  short* Pw = Ps[wave];

  stage(0, 0);
  __syncthreads();
  int cur = 0;
  for (int kt=0; kt<16; kt++){
    const int k0 = kt*64;
    if (kt < 15) stage(cur^1, k0 + 64);   // prefetch next tile, other buffer
    int mk[4];
    #pragma unroll
    for (int tj=0;tj<4;tj++) mk[tj] = mask[b*Gdim + k0 + tj*16 + l16];
    // ---- QK^T from LDS (swizzled reads)
    f4v sc[4];
    #pragma unroll
    for (int tj=0;tj<4;tj++) sc[tj] = f4v{0.f,0.f,0.f,0.f};
    const short* Kc = &Ks[cur][0];
    __builtin_amdgcn_s_setprio(1);
    #pragma unroll
    for (int st=0; st<8; st++){
      #pragma unroll
      for (int tj=0;tj<4;tj++){
        int row = tj*16 + l16;
        s8v kb = ld8(Kc + row*256 + (((st*4 + quad) ^ (row & 7)) << 3));
        sc[tj] = MFMA_BF16(qf[st], kb, sc[tj]);
      }
    }
    __builtin_amdgcn_s_setprio(0);
    // ---- online softmax; masked -> -30, stays in denominator, zeroed in
    //      numerator. Sum-reduce deferred: lsum is a PER-LANE partial.
    float al[4]; bool need = false;
    #pragma unroll
    for (int r=0;r<4;r++){
      float mx = -1e9f;
      #pragma unroll
      for (int tj=0;tj<4;tj++){
        float v = sc[tj][r] * 0.0625f;
        if (mk[tj]) v = -30.f;
        sc[tj][r] = v;
        mx = fmaxf(mx, v);
      }
      #pragma unroll
      for (int mm=1; mm<16; mm<<=1) mx = fmaxf(mx, __shfl_xor(mx, mm));
      float mn = fmaxf(mrow[r], mx);
      al[r] = __expf(mrow[r] - mn);
      need |= (al[r] < 1.f);
      mrow[r] = mn;
      float ps = 0.f;
      #pragma unroll
      for (int tj=0;tj<4;tj++){
        float e = __expf(sc[tj][r] - mn);
        ps += e;                         // masked entries stay in denominator
        sc[tj][r] = mk[tj] ? 0.f : e;    // zeroed in numerator
      }
      lsum[r] = lsum[r]*al[r] + ps;      // per-lane partial; no reduce here
    }
    if (__any(need)){
      #pragma unroll
      for (int t=0;t<16;t++)
        #pragma unroll
        for (int r=0;r<4;r++) O[t][r] *= al[r];
    }
    // ---- P transpose through wave-private LDS (intra-wave ordering only)
    #pragma unroll
    for (int tj=0;tj<4;tj++)
      #pragma unroll
      for (int r=0;r<4;r++)
        Pw[(quad*4 + r)*72 + tj*16 + l16] = f2bf(sc[tj][r]);
    asm volatile("s_waitcnt lgkmcnt(0)" ::: "memory");
    __builtin_amdgcn_sched_barrier(0);
    // ---- PV from LDS (swizzled reads)
    const short* Vc = &Vs[cur][0];
    __builtin_amdgcn_s_setprio(1);
    #pragma unroll
    for (int st=0; st<2; st++){
      s8v pa = ld8(&Pw[l16*72 + st*32 + quad*8]);
      #pragma unroll
      for (int tt=0; tt<16; tt++){
        int d = tt*16 + l16;
        s8v vb = ld8(Vc + d*64 + (((st*4 + quad) ^ (d & 7)) << 3));
        O[tt] = MFMA_BF16(pa, vb, O[tt]);
      }
    }
    __builtin_amdgcn_s_setprio(0);
    __syncthreads();   // drains vmcnt (prefetch done) + lgkm; flip safe
    cur ^= 1;
  }
  // ---- deferred cross-lane sum reduce (once, not per kt)
  float dn[4];
  #pragma unroll
  for (int r=0;r<4;r++){
    float s = lsum[r];
    #pragma unroll
    for (int mm=1; mm<16; mm<<=1) s += __shfl_xor(s, mm);
    dn[r] = fmaxf(s, 1e-30f);
  }
  #pragma unroll
  for (int t=0;t<16;t++){
    #pragma unroll
    for (int r=0;r<4;r++){
      int row = qbase + quad*4 + r;
      int col = t*16 + l16;
      H[((size_t)b*Gdim + row)*Ddim + col] = f2bf(O[t][r] / dn[r]);
    }
  }
}

// ------------------------------------------------------------ fused store + mean partial
// One pass over h32: writes output h (bf16/f32) AND accumulates 64-row
// partial sums -> part (replaces separate store_h + mean_partial).
__global__ __launch_bounds__(256) void store_mean(const float* __restrict__ h32,
                                                  void* __restrict__ out,
                                                  float* __restrict__ part,
                                                  const int* __restrict__ flag){
  int b = blockIdx.x, c = blockIdx.y, d = threadIdx.x;
  int fl = flag[0];
  float s = 0.f;
  for (int g = c*64; g < c*64 + 64; g++){
    size_t idx = ((size_t)b*Gdim + g)*Ddim + d;
    float v = h32[idx];
    s += v;
    if (fl) ((float*)out)[idx] = v;
    else    ((short*)out)[idx] = f2bf(v);
  }
  part[(b*16 + c)*Ddim + d] = s;
}
__global__ __launch_bounds__(256) void mean_final_dyn(const float* __restrict__ part,
                                                      void* __restrict__ out,
                                                      const int* __restrict__ flag){
  int i = blockIdx.x*256 + threadIdx.x;
  int b = i >> 8, d = i & 255;
  float s = 0.f;
  #pragma unroll
  for (int c=0;c<16;c++) s += part[(b*16 + c)*Ddim + d];
  s *= (1.f/1024.f);
  if (flag[0]) ((float*)out)[16777216 + i] = s;
  else         ((short*)out)[16777216 + i] = f2bf(s);
}

// ------------------------------------------------------------ launch
extern "C" void kernel_launch(void* const* d_in, const int* in_sizes, int n_in,
                              void* d_out, int out_size, void* d_ws, size_t ws_size,
                              hipStream_t stream)
{
  const void* xs  = d_in[0];
  const int*  mask= (const int*)d_in[1];
  const void* Wq  = d_in[2];
  const void* Wk  = d_in[3];
  const void* Wv  = d_in[4];
  const void* Wo  = d_in[5];
  const void* bo  = d_in[6];
  const void* Wf1 = d_in[7];
  const void* bf1 = d_in[8];
  const void* Wf2 = d_in[9];
  const void* bf2 = d_in[10];

  // weights: Wqkv(768K) + Wo(256K) + Wf1(1M) + Wf2(1M) + biasf(12K)
  const size_t W_ALL = 786432 + 262144 + 1048576 + 1048576 + 12288;  // 3,158,016
  const size_t BASE  = 256 + 67108864;                               // flag + h32
  int CB;
  if      (ws_size >= BASE + 134217728ull + W_ALL) CB = 64;   // 204.5 MB
  else if (ws_size >= BASE +  67108864ull + W_ALL) CB = 32;   // 137.4 MB (proven reachable)
  else if (ws_size >= BASE +  33554432ull + W_ALL) CB = 16;
  else CB = 0;

  char* p = (char*)d_ws;
  int* flag = (int*)p; p += 256;
  detect_dtype<<<1, 256, 0, stream>>>((const unsigned*)xs, flag);
  if (CB == 0){
    diag_ws<<<1, 64, 0, stream>>>(d_out, 2000.f + (float)(ws_size >> 20), flag);
    return;
  }
  const int M = CB * 1024, nch = 64 / CB;
  float* h32 = (float*)p; p += 67108864;
  char* arena = p;        p += (size_t)CB * 2097152;
  short* WqkvT = (short*)p; p += 786432;
  short* WoT   = (short*)p; p += 262144;
  short* Wf1T  = (short*)p; p += 1048576;
  short* Wf2T  = (short*)p; p += 1048576;
  float* biasf = (float*)p; p += 12288;
  float* part  = (float*)arena;          // arena dead by mean time

  short* Qc  = (short*)arena;
  short* Kc  = Qc + (size_t)M*256;
  short* Vtc = Qc + (size_t)2*M*256;
  short* Hc  = Qc + (size_t)3*M*256;     // QKV writes V row-major here first
  short* Tc  = Qc;                       // FFN intermediate spans whole arena

  cast_in<<<8192, 256, 0, stream>>>(xs, h32, flag);
  dim3 tb(32,8);
  transpose_w<<<dim3(8,8,2),  tb, 0, stream>>>(Wq,  WqkvT, 256, 256,  flag, 196608, 0);
  transpose_w<<<dim3(8,8,2),  tb, 0, stream>>>(Wk,  WqkvT, 256, 256,  flag, 196608, 65536);
  transpose_w<<<dim3(8,8,2),  tb, 0, stream>>>(Wv,  WqkvT, 256, 256,  flag, 196608, 131072);
  transpose_w<<<dim3(8,8,2),  tb, 0, stream>>>(Wo,  WoT,   256, 256,  flag, 65536, 0);
  transpose_w<<<dim3(32,8,2), tb, 0, stream>>>(Wf1, Wf1T,  256, 1024, flag, 262144, 0);
  transpose_w<<<dim3(8,32,2), tb, 0, stream>>>(Wf2, Wf2T,  1024, 256, flag, 262144, 0);
  bias_prep<<<12, 256, 0, stream>>>(bo, bf1, bf2, biasf, flag);

  for (int c=0; c<nch; c++){
    float* hc = h32 + (size_t)c*M*256;
    const int* mc = mask + (size_t)c*M;
    for (int l=0; l<2; l++){
      // fused QKV: A = h fp32 (hi), B = stacked [768][256]; V row-major -> Hc
      gemm_t<1,5><<<dim3(M/128,6), 256, 0, stream>>>(hc, WqkvT + l*196608, nullptr,
                                                     nullptr, Qc, 768, 256, 256, 256, M);
      // V row-major (Hc) -> V^T (Vtc), coalesced both sides
      transpose_v<<<dim3(8,32,CB), tb, 0, stream>>>(Hc, Vtc);
      flash_attn<<<dim3(8*CB), 512, 0, stream>>>(Qc, Kc, Vtc, mc, Hc);
      // O-proj: h32 += Hc*Wo + bo
      gemm_t<0,4><<<dim3(M/128,2), 256, 0, stream>>>(Hc, WoT + l*65536, biasf + l*256,
                                                     hc, nullptr, 256, 256, 256, 256, M);
      // FFN1: T = relu(h*Wf1 + b), A split
      gemm_t<2,1><<<dim3(M/128,8), 256, 0, stream>>>(hc, Wf1T + l*262144, biasf + 512 + l*1024,
                                                     nullptr, Tc, 1024, 256, 256, 256, M);
      // FFN2: h32 += T*Wf2 + b
      gemm_t<0,4><<<dim3(M/128,2), 256, 0, stream>>>(Tc, Wf2T + l*262144, biasf + 2560 + l*256,
                                                     hc, nullptr, 256, 1024, 1024, 1024, M);
    }
  }
  store_mean<<<dim3(64,16), 256, 0, stream>>>(h32, d_out, part, flag);
  mean_final_dyn<<<64, 256, 0, stream>>>(part, d_out, flag);
}

// Round 12
// 1027.918 us; speedup vs baseline: 1.1943x; 1.1165x over previous
//
#include <hip/hip_runtime.h>
#include <hip/hip_bf16.h>

#define Bdim 64
#define Gdim 1024
#define Ddim 256
#define Fdim 1024

typedef short s8v __attribute__((ext_vector_type(8)));
typedef short s4v __attribute__((ext_vector_type(4)));
typedef float f4v __attribute__((ext_vector_type(4)));

__device__ __forceinline__ float bf2f(short s){
  return __uint_as_float(((unsigned)(unsigned short)s) << 16);
}
__device__ __forceinline__ short f2bf(float f){
  unsigned u = __float_as_uint(f);
  u = u + 0x7fffu + ((u >> 16) & 1u);   // RNE
  return (short)(u >> 16);
}
__device__ __forceinline__ s8v ld8(const short* p){ return *(const s8v*)p; }

#define MFMA_BF16(a,b,c) __builtin_amdgcn_mfma_f32_16x16x32_bf16((a),(b),(c),0,0,0)

// async 16B global->LDS (linear dest; swizzle done on the SOURCE address)
#define GLDS16(gp, lp) __builtin_amdgcn_global_load_lds( \
    (const __attribute__((address_space(1))) void*)(gp), \
    (__attribute__((address_space(3))) void*)(lp), 16, 0, 0)

// ------------------------------------------------------------ dtype detection
__global__ __launch_bounds__(256) void detect_dtype(const unsigned* __restrict__ x,
                                                    int* __restrict__ flag){
  __shared__ int cnt[256];
  int c = 0;
  #pragma unroll
  for (int j=0;j<4;j++){
    unsigned u = x[threadIdx.x*4 + j];
    int e = (u >> 7) & 0xFF;
    c += (e >= 100 && e <= 140) ? 1 : 0;
  }
  cnt[threadIdx.x] = c;
  __syncthreads();
  if (threadIdx.x == 0){
    int s = 0;
    for (int i=0;i<256;i++) s += cnt[i];
    flag[0] = (s >= 512) ? 0 : 1;   // 0 = bf16 inputs, 1 = fp32 inputs
  }
}

// ------------------------------------------------------------ diagnostic
__global__ void diag_ws(void* o, float v, const int* __restrict__ flag){
  if (threadIdx.x == 0){
    if (flag[0]){ ((float*)o)[0] = v; ((float*)o)[16777216] = v; }
    else        { ((short*)o)[0] = f2bf(v); ((short*)o)[16777216] = f2bf(v); }
  }
}

// ------------------------------------------------------------ input -> fp32 h
__global__ __launch_bounds__(256) void cast_in(const void* __restrict__ x,
                                               float* __restrict__ h32,
                                               const int* __restrict__ flag){
  size_t i = ((size_t)blockIdx.x * 256 + threadIdx.x) * 8;
  if (flag[0]){
    const float* xf = (const float*)x;
    #pragma unroll
    for (int j=0;j<8;j++) h32[i+j] = xf[i+j];
  } else {
    s8v v = ld8((const short*)x + i);
    #pragma unroll
    for (int j=0;j<8;j++) h32[i+j] = bf2f(v[j]);
  }
}

// ------------------------------------------------------------ weight transpose -> bf16, stackable dst
__global__ __launch_bounds__(256) void transpose_w(const void* __restrict__ src,
                                                   short* __restrict__ dh, int R, int C,
                                                   const int* __restrict__ flag,
                                                   int dzs, int dbase){
  __shared__ short th[32][33];
  int fl = flag[0];
  size_t soff = (size_t)blockIdx.z * R * C;
  size_t doff = (size_t)dbase + (size_t)blockIdx.z * dzs;
  int c0 = blockIdx.x*32, r0 = blockIdx.y*32;
  int tx = threadIdx.x, ty = threadIdx.y;
  #pragma unroll
  for (int i=ty;i<32;i+=8){
    size_t idx = soff + (size_t)(r0+i)*C + (c0+tx);
    float w = fl ? ((const float*)src)[idx] : bf2f(((const short*)src)[idx]);
    th[i][tx] = f2bf(w);
  }
  __syncthreads();
  #pragma unroll
  for (int i=ty;i<32;i+=8)
    dh[doff + (size_t)(c0+i)*R + (r0+tx)] = th[tx][i];
}

// ------------------------------------------------------------ V row-major -> V^T (bf16), per batch
// src: [CB][1024 g][256 d] row-major; dst: [CB][256 d][1024 g]
__global__ __launch_bounds__(256) void transpose_v(const short* __restrict__ src,
                                                   short* __restrict__ dst){
  __shared__ short th[32][33];
  const short* s = src + (size_t)blockIdx.z * 262144;
  short* dd      = dst + (size_t)blockIdx.z * 262144;
  int d0 = blockIdx.x*32, g0 = blockIdx.y*32;
  int tx = threadIdx.x, ty = threadIdx.y;
  #pragma unroll
  for (int i=ty;i<32;i+=8)
    th[i][tx] = s[(size_t)(g0+i)*256 + d0 + tx];
  __syncthreads();
  #pragma unroll
  for (int i=ty;i<32;i+=8)
    dd[(size_t)(d0+i)*1024 + g0 + tx] = th[tx][i];
}

// ------------------------------------------------------------ biases -> fp32
// [0..511]=bo(2x256)  [512..2559]=bf1(2x1024)  [2560..3071]=bf2(2x256)
__global__ __launch_bounds__(256) void bias_prep(const void* __restrict__ bo,
                                                 const void* __restrict__ bf1,
                                                 const void* __restrict__ bf2,
                                                 float* __restrict__ biasf,
                                                 const int* __restrict__ flag){
  int fl = flag[0];
  int i = blockIdx.x*256 + threadIdx.x;
  const void* src; int idx;
  if (i < 512){ src = bo; idx = i; }
  else if (i < 2560){ src = bf1; idx = i - 512; }
  else { src = bf2; idx = i - 2560; }
  biasf[i] = fl ? ((const float*)src)[idx] : bf2f(((const short*)src)[idx]);
}

// ------------------------------------------------------------ GEMM template (v3: m97 pipeline + XCD swizzle)
// Double-buffered A/B LDS tiles [2][128][32] (linear dest for global_load_lds,
// XOR slot-swizzle slot^(row&3) applied on SOURCE addresses and on reads).
// B always bf16 -> GLDS16. A: AM=0 -> GLDS16; AM=1/2 -> reg-stage.
// ONE __syncthreads per K-step. XCD-AWARE BLOCK SWIZZLE (T1): all gridDim.y
// N-tiles of an M-panel map to consecutive slots on the SAME XCD (HW
// round-robins linear block id % 8) -> A-panel fetched from HBM once per
// M-panel, remaining N-tiles hit that XCD's L2. Bijective since gridDim.x
// is always a multiple of 8 here.
// AM: 0 = A bf16; 1 = A fp32 -> hi only; 2 = A fp32 -> hi+lo split (2 MFMA)
// EPI: 0 = bf16 store; 1 = relu(acc+bias) bf16 store;
//      4 = h32[idx] += acc + bias; 5 = fused QKV routing (Q,K,V row-major)
template<int AM, int EPI>
__global__ __launch_bounds__(256) void gemm_t(
    const void* __restrict__ Ap, const short* __restrict__ Bh,
    const float* __restrict__ bias, float* __restrict__ hout,
    short* __restrict__ outb, int N, int K, int lda, int ldb, int Mrows)
{
  __shared__ short As[2][128*32];
  __shared__ short Bs[2][128*32];
  __shared__ short Asl[(AM==2)?2:1][(AM==2)?128*32:1];
  const int tid = threadIdx.x;
  const int lane = tid & 63, wave = tid >> 6;
  const int quad = lane >> 4, l16 = lane & 15;
  // XCD-aware swizzle: lid%8 = XCD; give each XCD whole M-panels, n fastest.
  const int NYt = gridDim.y;
  const int lid = blockIdx.x + gridDim.x * blockIdx.y;
  const int xcd = lid & 7, slot = lid >> 3;
  const int m0 = (xcd + 8 * (slot / NYt)) * 128;
  const int n0 = (slot % NYt) * 128;
  const int wr = wave >> 1, wc = wave & 1;
  const int roff = ((quad ^ (l16 & 3)) << 3);   // read-side swizzled 16B slot
  f4v acc[4][4];
  #pragma unroll
  for (int i=0;i<4;i++)
    #pragma unroll
    for (int j=0;j<4;j++) acc[i][j] = f4v{0.f,0.f,0.f,0.f};

  // per-thread staging geometry: 512 x 16B chunks per tile, 2 per thread
  int rr[2], ss[2], dst[2];
  #pragma unroll
  for (int i=0;i<2;i++){
    int idx = i*256 + tid;
    rr[i] = idx >> 2;
    ss[i] = (idx & 3) ^ (rr[i] & 3);   // source slot (inverse swizzle)
    dst[i] = idx * 8;                  // dest short index (linear)
  }

  auto stageB = [&](int buf, int k0){
    #pragma unroll
    for (int i=0;i<2;i++)
      GLDS16(Bh + (size_t)(n0 + rr[i])*ldb + k0 + ss[i]*8, &Bs[buf][dst[i]]);
  };
  auto stageA0 = [&](int buf, int k0){
    #pragma unroll
    for (int i=0;i<2;i++)
      GLDS16((const short*)Ap + (size_t)(m0 + rr[i])*lda + k0 + ss[i]*8, &As[buf][dst[i]]);
  };

  const int T = K >> 5;
  int cur = 0;
  // prologue: stage tile 0
  float4 pf0a, pf0b, pf1a, pf1b;
  stageB(0, 0);
  if (AM == 0){
    stageA0(0, 0);
  } else {
    #pragma unroll
    for (int i=0;i<2;i++){
      const float* ap = (const float*)Ap + (size_t)(m0 + rr[i])*lda + ss[i]*8;
      float4 a = *(const float4*)ap, b = *(const float4*)(ap + 4);
      float fv[8] = {a.x,a.y,a.z,a.w,b.x,b.y,b.z,b.w};
      s8v hi, lo;
      #pragma unroll
      for (int j=0;j<8;j++) hi[j] = f2bf(fv[j]);
      *(s8v*)(&As[0][dst[i]]) = hi;
      if (AM == 2){
        #pragma unroll
        for (int j=0;j<8;j++) lo[j] = f2bf(fv[j] - bf2f(hi[j]));
        *(s8v*)(&Asl[0][dst[i]]) = lo;
      }
    }
  }

  for (int t = 0; t < T; ++t){
    __syncthreads();                   // stage(cur) complete; prev reads done
    const int nk = (t + 1) << 5;
    if (t + 1 < T){                    // issue next-tile staging early
      stageB(cur ^ 1, nk);
      if (AM == 0){
        stageA0(cur ^ 1, nk);
      } else {
        const float* ap0 = (const float*)Ap + (size_t)(m0 + rr[0])*lda + nk + ss[0]*8;
        const float* ap1 = (const float*)Ap + (size_t)(m0 + rr[1])*lda + nk + ss[1]*8;
        pf0a = *(const float4*)ap0; pf0b = *(const float4*)(ap0 + 4);
        pf1a = *(const float4*)ap1; pf1b = *(const float4*)(ap1 + 4);
      }
    }
    // fragments from cur (swizzled reads)
    s8v ah[4], al[4], bh[4];
    #pragma unroll
    for (int q=0;q<4;q++){
      ah[q] = ld8(&As[cur][(wr*64 + q*16 + l16)*32 + roff]);
      bh[q] = ld8(&Bs[cur][(wc*64 + q*16 + l16)*32 + roff]);
      if (AM == 2) al[q] = ld8(&Asl[cur][(wr*64 + q*16 + l16)*32 + roff]);
    }
    __builtin_amdgcn_s_setprio(1);
    #pragma unroll
    for (int ti=0;ti<4;ti++)
      #pragma unroll
      for (int tj=0;tj<4;tj++){
        acc[ti][tj] = MFMA_BF16(ah[ti], bh[tj], acc[ti][tj]);
        if (AM == 2) acc[ti][tj] = MFMA_BF16(al[ti], bh[tj], acc[ti][tj]);
      }
    __builtin_amdgcn_s_setprio(0);
    if (AM != 0 && t + 1 < T){         // convert + write A(t+1) after compute
      float fv0[8] = {pf0a.x,pf0a.y,pf0a.z,pf0a.w,pf0b.x,pf0b.y,pf0b.z,pf0b.w};
      float fv1[8] = {pf1a.x,pf1a.y,pf1a.z,pf1a.w,pf1b.x,pf1b.y,pf1b.z,pf1b.w};
      s8v hi0, hi1, lo0, lo1;
      #pragma unroll
      for (int j=0;j<8;j++){ hi0[j] = f2bf(fv0[j]); hi1[j] = f2bf(fv1[j]); }
      *(s8v*)(&As[cur^1][dst[0]]) = hi0;
      *(s8v*)(&As[cur^1][dst[1]]) = hi1;
      if (AM == 2){
        #pragma unroll
        for (int j=0;j<8;j++){
          lo0[j] = f2bf(fv0[j] - bf2f(hi0[j]));
          lo1[j] = f2bf(fv1[j] - bf2f(hi1[j]));
        }
        *(s8v*)(&Asl[cur^1][dst[0]]) = lo0;
        *(s8v*)(&Asl[cur^1][dst[1]]) = lo1;
      }
    }
    cur ^= 1;
  }
  #pragma unroll
  for (int tj=0;tj<4;tj++){
    int col = n0 + wc*64 + tj*16 + l16;
    float bs = (EPI==1 || EPI==4) ? (bias ? bias[col] : 0.f) : 0.f;
    #pragma unroll
    for (int ti=0;ti<4;ti++){
      #pragma unroll
      for (int r=0;r<4;r++){
        int row = m0 + wr*64 + ti*16 + quad*4 + r;
        float v = acc[ti][tj][r];
        if (EPI == 0){
          outb[(size_t)row * N + col] = f2bf(v);
        } else if (EPI == 1){
          v += bs; v = v > 0.f ? v : 0.f;
          outb[(size_t)row * N + col] = f2bf(v);
        } else if (EPI == 4){
          size_t idx = (size_t)row * N + col;
          hout[idx] += v + bs;
        } else {  // EPI == 5: fused QKV; V goes ROW-MAJOR into the Hc slot
          int sec = col >> 8, c = col & 255;
          if (sec == 0)      outb[(size_t)row*256 + c] = f2bf(v);
          else if (sec == 1) (outb + (size_t)Mrows*256)[(size_t)row*256 + c] = f2bf(v);
          else               (outb + (size_t)3*Mrows*256)[(size_t)row*256 + c] = f2bf(v);
        }
      }
    }
  }
}

// ------------------------------------------------------------ flash attention v4 (best measured 142.7us)
// 8 waves x 16 q-rows = 128 rows/block; 8 blocks/batch; grid 8*CB; 512 thr ->
// 8 waves/CU = 2 waves/SIMD. K,V double-buffered in LDS via async
// global_load_lds (linear dest, XOR-pre-swizzled SOURCE, same XOR on ds_read).
// One __syncthreads per kt. Sum-reduce DEFERRED: per-lane partial lsum with
// the same rescale recurrence; single cross-lane reduce in the epilogue.
// setprio(1) wraps MFMA clusters.
__global__ __launch_bounds__(512, 2) void flash_attn(
    const short* __restrict__ Q, const short* __restrict__ Kmat,
    const short* __restrict__ Vt, const int* __restrict__ mask,
    short* __restrict__ H)
{
  __shared__ short Ks[2][64*256];   // 64 KiB: K tile [64 keys][256 d], src-swizzled
  __shared__ short Vs[2][256*64];   // 64 KiB: V^T tile [256 d][64 keys], src-swizzled
  __shared__ short Ps[8][16*72];    // 18 KiB: per-wave P [16 qrows][64 keys]
  const int tid = threadIdx.x;
  const int lane = tid & 63, wave = tid >> 6;   // wave 0..7
  const int quad = lane >> 4, l16 = lane & 15;
  // batch -> XCD pinning: all 8 q-tile blocks of batch b share XCD b&7.
  const int bid = blockIdx.x;
  const int b  = (bid & 7) + ((bid >> 6) << 3);
  const int qt = (bid >> 3) & 7;
  const short* Qb  = Q    + (size_t)b*Gdim*Ddim;
  const short* Kb  = Kmat + (size_t)b*Gdim*Ddim;
  const short* Vtb = Vt   + (size_t)b*Ddim*Gdim;
  const int qbase = qt*128 + wave*16;

  auto stage = [&](int buf, int k0){
    #pragma unroll
    for (int i=0;i<4;i++){            // K tile: 32 KiB, 16B/thread x 4
      int idx = i*512 + tid;
      int r = idx >> 5, g = idx & 31;
      GLDS16(Kb + (size_t)(k0 + r)*Ddim + ((g ^ (r & 7)) << 3), &Ks[buf][idx*8]);
    }
    #pragma unroll
    for (int i=0;i<4;i++){            // V^T tile: 32 KiB
      int idx = i*512 + tid;
      int d = idx >> 3, g = idx & 7;
      GLDS16(Vtb + (size_t)d*Gdim + k0 + ((g ^ (d & 7)) << 3), &Vs[buf][idx*8]);
    }
  };

  s8v qf[8];
  #pragma unroll
  for (int s=0;s<8;s++)
    qf[s] = ld8(Qb + (size_t)(qbase + l16)*Ddim + s*32 + quad*8);
  float mrow[4], lsum[4];
  #pragma unroll
  for (int r=0;r<4;r++){ mrow[r] = -1e9f; lsum[r] = 0.f; }
  f4v O[16];
  #pragma unroll
  for (int t=0;t<16;t++) O[t] = f4v{0.f,0.f,0.f,0.f};
  short* Pw = Ps[wave];

  stage(0, 0);
  __syncthreads();
  int cur = 0;
  for (int kt=0; kt<16; kt++){
    const int k0 = kt*64;
    if (kt < 15) stage(cur^1, k0 + 64);   // prefetch next tile, other buffer
    int mk[4];
    #pragma unroll
    for (int tj=0;tj<4;tj++) mk[tj] = mask[b*Gdim + k0 + tj*16 + l16];
    // ---- QK^T from LDS (swizzled reads)
    f4v sc[4];
    #pragma unroll
    for (int tj=0;tj<4;tj++) sc[tj] = f4v{0.f,0.f,0.f,0.f};
    const short* Kc = &Ks[cur][0];
    __builtin_amdgcn_s_setprio(1);
    #pragma unroll
    for (int st=0; st<8; st++){
      #pragma unroll
      for (int tj=0;tj<4;tj++){
        int row = tj*16 + l16;
        s8v kb = ld8(Kc + row*256 + (((st*4 + quad) ^ (row & 7)) << 3));
        sc[tj] = MFMA_BF16(qf[st], kb, sc[tj]);
      }
    }
    __builtin_amdgcn_s_setprio(0);
    // ---- online softmax; masked -> -30, stays in denominator, zeroed in
    //      numerator. Sum-reduce deferred: lsum is a PER-LANE partial.
    float al[4]; bool need = false;
    #pragma unroll
    for (int r=0;r<4;r++){
      float mx = -1e9f;
      #pragma unroll
      for (int tj=0;tj<4;tj++){
        float v = sc[tj][r] * 0.0625f;
        if (mk[tj]) v = -30.f;
        sc[tj][r] = v;
        mx = fmaxf(mx, v);
      }
      #pragma unroll
      for (int mm=1; mm<16; mm<<=1) mx = fmaxf(mx, __shfl_xor(mx, mm));
      float mn = fmaxf(mrow[r], mx);
      al[r] = __expf(mrow[r] - mn);
      need |= (al[r] < 1.f);
      mrow[r] = mn;
      float ps = 0.f;
      #pragma unroll
      for (int tj=0;tj<4;tj++){
        float e = __expf(sc[tj][r] - mn);
        ps += e;                         // masked entries stay in denominator
        sc[tj][r] = mk[tj] ? 0.f : e;    // zeroed in numerator
      }
      lsum[r] = lsum[r]*al[r] + ps;      // per-lane partial; no reduce here
    }
    if (__any(need)){
      #pragma unroll
      for (int t=0;t<16;t++)
        #pragma unroll
        for (int r=0;r<4;r++) O[t][r] *= al[r];
    }
    // ---- P transpose through wave-private LDS (intra-wave ordering only)
    #pragma unroll
    for (int tj=0;tj<4;tj++)
      #pragma unroll
      for (int r=0;r<4;r++)
        Pw[(quad*4 + r)*72 + tj*16 + l16] = f2bf(sc[tj][r]);
    asm volatile("s_waitcnt lgkmcnt(0)" ::: "memory");
    __builtin_amdgcn_sched_barrier(0);
    // ---- PV from LDS (swizzled reads)
    const short* Vc = &Vs[cur][0];
    __builtin_amdgcn_s_setprio(1);
    #pragma unroll
    for (int st=0; st<2; st++){
      s8v pa = ld8(&Pw[l16*72 + st*32 + quad*8]);
      #pragma unroll
      for (int tt=0; tt<16; tt++){
        int d = tt*16 + l16;
        s8v vb = ld8(Vc + d*64 + (((st*4 + quad) ^ (d & 7)) << 3));
        O[tt] = MFMA_BF16(pa, vb, O[tt]);
      }
    }
    __builtin_amdgcn_s_setprio(0);
    __syncthreads();   // drains vmcnt (prefetch done) + lgkm; flip safe
    cur ^= 1;
  }
  // ---- deferred cross-lane sum reduce (once, not per kt)
  float dn[4];
  #pragma unroll
  for (int r=0;r<4;r++){
    float s = lsum[r];
    #pragma unroll
    for (int mm=1; mm<16; mm<<=1) s += __shfl_xor(s, mm);
    dn[r] = fmaxf(s, 1e-30f);
  }
  #pragma unroll
  for (int t=0;t<16;t++){
    #pragma unroll
    for (int r=0;r<4;r++){
      int row = qbase + quad*4 + r;
      int col = t*16 + l16;
      H[((size_t)b*Gdim + row)*Ddim + col] = f2bf(O[t][r] / dn[r]);
    }
  }
}

// ------------------------------------------------------------ fused store + mean partial
// One pass over h32: writes output h (bf16/f32) AND accumulates 64-row
// partial sums -> part (replaces separate store_h + mean_partial).
__global__ __launch_bounds__(256) void store_mean(const float* __restrict__ h32,
                                                  void* __restrict__ out,
                                                  float* __restrict__ part,
                                                  const int* __restrict__ flag){
  int b = blockIdx.x, c = blockIdx.y, d = threadIdx.x;
  int fl = flag[0];
  float s = 0.f;
  for (int g = c*64; g < c*64 + 64; g++){
    size_t idx = ((size_t)b*Gdim + g)*Ddim + d;
    float v = h32[idx];
    s += v;
    if (fl) ((float*)out)[idx] = v;
    else    ((short*)out)[idx] = f2bf(v);
  }
  part[(b*16 + c)*Ddim + d] = s;
}
__global__ __launch_bounds__(256) void mean_final_dyn(const float* __restrict__ part,
                                                      void* __restrict__ out,
                                                      const int* __restrict__ flag){
  int i = blockIdx.x*256 + threadIdx.x;
  int b = i >> 8, d = i & 255;
  float s = 0.f;
  #pragma unroll
  for (int c=0;c<16;c++) s += part[(b*16 + c)*Ddim + d];
  s *= (1.f/1024.f);
  if (flag[0]) ((float*)out)[16777216 + i] = s;
  else         ((short*)out)[16777216 + i] = f2bf(s);
}

// ------------------------------------------------------------ launch
extern "C" void kernel_launch(void* const* d_in, const int* in_sizes, int n_in,
                              void* d_out, int out_size, void* d_ws, size_t ws_size,
                              hipStream_t stream)
{
  const void* xs  = d_in[0];
  const int*  mask= (const int*)d_in[1];
  const void* Wq  = d_in[2];
  const void* Wk  = d_in[3];
  const void* Wv  = d_in[4];
  const void* Wo  = d_in[5];
  const void* bo  = d_in[6];
  const void* Wf1 = d_in[7];
  const void* bf1 = d_in[8];
  const void* Wf2 = d_in[9];
  const void* bf2 = d_in[10];

  // weights: Wqkv(768K) + Wo(256K) + Wf1(1M) + Wf2(1M) + biasf(12K)
  const size_t W_ALL = 786432 + 262144 + 1048576 + 1048576 + 12288;  // 3,158,016
  const size_t BASE  = 256 + 67108864;                               // flag + h32
  int CB;
  if      (ws_size >= BASE + 134217728ull + W_ALL) CB = 64;   // 204.5 MB
  else if (ws_size >= BASE +  67108864ull + W_ALL) CB = 32;   // 137.4 MB (proven reachable)
  else if (ws_size >= BASE +  33554432ull + W_ALL) CB = 16;
  else CB = 0;

  char* p = (char*)d_ws;
  int* flag = (int*)p; p += 256;
  detect_dtype<<<1, 256, 0, stream>>>((const unsigned*)xs, flag);
  if (CB == 0){
    diag_ws<<<1, 64, 0, stream>>>(d_out, 2000.f + (float)(ws_size >> 20), flag);
    return;
  }
  const int M = CB * 1024, nch = 64 / CB;
  float* h32 = (float*)p; p += 67108864;
  char* arena = p;        p += (size_t)CB * 2097152;
  short* WqkvT = (short*)p; p += 786432;
  short* WoT   = (short*)p; p += 262144;
  short* Wf1T  = (short*)p; p += 1048576;
  short* Wf2T  = (short*)p; p += 1048576;
  float* biasf = (float*)p; p += 12288;
  float* part  = (float*)arena;          // arena dead by mean time

  short* Qc  = (short*)arena;
  short* Kc  = Qc + (size_t)M*256;
  short* Vtc = Qc + (size_t)2*M*256;
  short* Hc  = Qc + (size_t)3*M*256;     // QKV writes V row-major here first
  short* Tc  = Qc;                       // FFN intermediate spans whole arena

  cast_in<<<8192, 256, 0, stream>>>(xs, h32, flag);
  dim3 tb(32,8);
  transpose_w<<<dim3(8,8,2),  tb, 0, stream>>>(Wq,  WqkvT, 256, 256,  flag, 196608, 0);
  transpose_w<<<dim3(8,8,2),  tb, 0, stream>>>(Wk,  WqkvT, 256, 256,  flag, 196608, 65536);
  transpose_w<<<dim3(8,8,2),  tb, 0, stream>>>(Wv,  WqkvT, 256, 256,  flag, 196608, 131072);
  transpose_w<<<dim3(8,8,2),  tb, 0, stream>>>(Wo,  WoT,   256, 256,  flag, 65536, 0);
  transpose_w<<<dim3(32,8,2), tb, 0, stream>>>(Wf1, Wf1T,  256, 1024, flag, 262144, 0);
  transpose_w<<<dim3(8,32,2), tb, 0, stream>>>(Wf2, Wf2T,  1024, 256, flag, 262144, 0);
  bias_prep<<<12, 256, 0, stream>>>(bo, bf1, bf2, biasf, flag);

  for (int c=0; c<nch; c++){
    float* hc = h32 + (size_t)c*M*256;
    const int* mc = mask + (size_t)c*M;
    for (int l=0; l<2; l++){
      // fused QKV: A = h fp32 (hi), B = stacked [768][256]; V row-major -> Hc
      gemm_t<1,5><<<dim3(M/128,6), 256, 0, stream>>>(hc, WqkvT + l*196608, nullptr,
                                                     nullptr, Qc, 768, 256, 256, 256, M);
      // V row-major (Hc) -> V^T (Vtc), coalesced both sides
      transpose_v<<<dim3(8,32,CB), tb, 0, stream>>>(Hc, Vtc);
      flash_attn<<<dim3(8*CB), 512, 0, stream>>>(Qc, Kc, Vtc, mc, Hc);
      // O-proj: h32 += Hc*Wo + bo
      gemm_t<0,4><<<dim3(M/128,2), 256, 0, stream>>>(Hc, WoT + l*65536, biasf + l*256,
                                                     hc, nullptr, 256, 256, 256, 256, M);
      // FFN1: T = relu(h*Wf1 + b), A split
      gemm_t<2,1><<<dim3(M/128,8), 256, 0, stream>>>(hc, Wf1T + l*262144, biasf + 512 + l*1024,
                                                     nullptr, Tc, 1024, 256, 256, 256, M);
      // FFN2: h32 += T*Wf2 + b
      gemm_t<0,4><<<dim3(M/128,2), 256, 0, stream>>>(Tc, Wf2T + l*262144, biasf + 2560 + l*256,
                                                     hc, nullptr, 256, 1024, 1024, 1024, M);
    }
  }
  store_mean<<<dim3(64,16), 256, 0, stream>>>(h32, d_out, part, flag);
  mean_final_dyn<<<64, 256, 0, stream>>>(part, d_out, flag);
}